// Round 7
// baseline (90.312 us; speedup 1.0000x reference)
//
#include <hip/hip_runtime.h>

#define S 24
#define PLANE 576
#define CISTRIDE 331776          // floats per (n,ci)
#define SLAB_B 21632             // 676 positions * 32 B
#define A_BYTES 46080            // 9 taps * 5 steps * 64 lanes * 16 B
#define WS_SLABS A_BYTES

typedef __attribute__((ext_vector_type(8))) short bf16x8;
typedef __attribute__((ext_vector_type(4))) float f32x4;

__device__ __forceinline__ ushort f2bf(float f) {   // round-to-nearest-even
    unsigned int u = __builtin_bit_cast(unsigned int, f);
    unsigned int r = u + 0x7fffu + ((u >> 16) & 1u);
    return (ushort)(r >> 16);
}

// slot swizzle: byte offset for (row,col,half) = ((row*26+col)*32 + half*16) ^ ((row&3)<<4)
__device__ __forceinline__ int swz(int row, int col, int half) {
    return (((row * 26 + col) * 32) + half * 16) ^ ((row & 3) << 4);
}

// ---------------- prepass: pack input slabs via LDS transpose (+ weights from block 0) ----
__global__ void __launch_bounds__(256)
pack_in(const float* __restrict__ in, const float* __restrict__ wgt, char* __restrict__ ws) {
    __shared__ unsigned lds_t[16][288];   // [ci][pos-pair] packed bf16x2 (two positions, one ci)

    const int b = blockIdx.x;             // 1152 slabs
    const int nb = b / PLANE, uv = b % PLANE;
    const float* src = in + (size_t)nb * 16 * CISTRIDE + (size_t)uv * PLANE;
    char* dst = ws + WS_SLABS + (size_t)b * SLAB_B;
    const int t = threadIdx.x;

    // phase 1: coalesced global float4 reads, bf16-pack, LDS b64 writes
    #pragma unroll
    for (int i = 0; i < 9; ++i) {
        int flat = i * 256 + t;           // 0..2303 float4 chunks
        int ci = flat / 144, q4 = flat % 144;
        float4 f = *(const float4*)(src + (size_t)ci * CISTRIDE + 4 * q4);
        uint2 pk;
        pk.x = (unsigned)f2bf(f.x) | ((unsigned)f2bf(f.y) << 16);
        pk.y = (unsigned)f2bf(f.z) | ((unsigned)f2bf(f.w) << 16);
        *(uint2*)&lds_t[ci][2 * q4] = pk;
    }
    __syncthreads();

    // phase 2: assemble swizzled 16B chunks, linear coalesced global writes
    #pragma unroll
    for (int i = 0; i < 6; ++i) {
        int c = i * 256 + t;              // chunk index 0..1351
        if (c < 1352) {
            int k = c >> 2;
            int row = k / 13;             // pairs never cross a row (26 even)
            int pos2 = c ^ (row & 3);
            int pos = pos2 >> 1, h = pos2 & 1;
            int col = pos - row * 26;
            uint4 o = make_uint4(0, 0, 0, 0);
            if (row >= 1 && row <= 24 && col >= 1 && col <= 24) {
                int q = (row - 1) * 24 + (col - 1);
                int q2 = q >> 1, odd = q & 1;
                #pragma unroll
                for (int kk = 0; kk < 4; ++kk) {
                    unsigned a = lds_t[8 * h + 2 * kk][q2];
                    unsigned bb = lds_t[8 * h + 2 * kk + 1][q2];
                    unsigned val = odd ? ((a >> 16) | (bb & 0xffff0000u))
                                       : ((a & 0xffffu) | (bb << 16));
                    ((unsigned*)&o)[kk] = val;
                }
            }
            *(uint4*)(dst + (size_t)c * 16) = o;
        }
    }

    if (b == 0) {                        // weight A-fragments -> ws[0..A_BYTES)
        for (int i = t; i < 2880; i += 256) {
            int step = i >> 6;           // 0..44
            int tap = step / 5, s = step % 5;
            int lane = i & 63;
            int co = lane & 15, gA = lane >> 4;
            int o = 2 * s + (gA >> 1);
            int cib = (gA & 1) * 8;
            ushort vals[8];
            #pragma unroll
            for (int j = 0; j < 8; ++j)
                vals[j] = (o <= 8) ? f2bf(wgt[co * 1296 + (cib + j) * 81 + tap * 9 + o]) : (ushort)0;
            uint4 pk;
            pk.x = vals[0] | ((unsigned)vals[1] << 16);
            pk.y = vals[2] | ((unsigned)vals[3] << 16);
            pk.z = vals[4] | ((unsigned)vals[5] << 16);
            pk.w = vals[6] | ((unsigned)vals[7] << 16);
            *(uint4*)(ws + (size_t)i * 16) = pk;
        }
    }
}

// ---------------- main kernel: G=2 v-adjacent output slabs per block ----------------
__global__ void __launch_bounds__(256, 2)
conv4d_main(const char* __restrict__ ws, const float* __restrict__ bias,
            float* __restrict__ out) {
    __shared__ __align__(16) char lds[2 * SLAB_B];   // 43264 B double buffer

    const int t = threadIdx.x, lane = t & 63, wvid = t >> 6;
    // XCD-chunked bijective swizzle: 576 work ids, 8 XCDs x 72 contiguous
    const int braw = blockIdx.x;
    const int b = (braw & 7) * 72 + (braw >> 3);
    const int nb = b / 288, rem = b % 288;
    const int u = rem / 12, v0 = (rem % 12) * 2;

    const int n16 = lane & 15, g = lane >> 4;
    const int dh = n16 >> 2, dw = n16 & 3;
    const int half = g & 1, osel = g >> 1;

    int laneoff[5];
    #pragma unroll
    for (int s = 0; s < 5; ++s) {
        int o = 2 * s + osel; if (o > 8) o = 8;      // K-tail clamp (A is zero there)
        int kh = o / 3, kw = o % 3;
        laneoff[s] = swz(dh + kh, dw + kw, half);
    }
    const int wv_off = (wvid >> 1) * 9984 + (wvid & 1) * 384;  // 12-row / 12-col quadrant

    f32x4 acc0[9], acc1[9];
    #pragma unroll
    for (int i = 0; i < 9; ++i) { acc0[i] = (f32x4){0,0,0,0}; acc1[i] = (f32x4){0,0,0,0}; }

    // valid-slab mask: i = 4*(uu-u+1) + (vv-v0+1)
    unsigned mask = 0;
    #pragma unroll
    for (int i = 0; i < 12; ++i) {
        int uu = u + (i >> 2) - 1, vv = v0 + (i & 3) - 1;
        if (uu >= 0 && uu < S && vv >= 0 && vv < S) mask |= 1u << i;
    }

    const char* slabs = ws + WS_SLABS;
    #define SLAB_PTR(i_) (slabs + ((size_t)nb * PLANE + (u + ((i_) >> 2) - 1) * S + (v0 + ((i_) & 3) - 1)) * SLAB_B)

    #define STAGE(bufsel_, src_) do {                                              \
        const char* _s = (src_);                                                   \
        _Pragma("unroll")                                                          \
        for (int r2 = 0; r2 < 6; ++r2) {                                           \
            int chunk = r2 * 256 + t;                                              \
            if (r2 < 5 || t < 72)                                                  \
                __builtin_amdgcn_global_load_lds(                                  \
                    (const __attribute__((address_space(1))) unsigned int*)(_s + (size_t)chunk * 16), \
                    (__attribute__((address_space(3))) unsigned int*)(lds + (bufsel_) * SLAB_B + chunk * 16), \
                    16, 0, 0);                                                     \
        }                                                                          \
    } while (0)

    const bf16x8 zfr = {0,0,0,0,0,0,0,0};

    int cur = __ffs(mask) - 1;
    int bufsel = 0;
    STAGE(0, SLAB_PTR(cur));
    __syncthreads();

    while (1) {
        unsigned remm = mask >> (cur + 1);
        int nxt = remm ? (cur + 1 + __ffs(remm) - 1) : -1;
        if (nxt >= 0) STAGE(bufsel ^ 1, SLAB_PTR(nxt));   // overlaps compute below

        const int ku = cur >> 2, dv = (cur & 3) - 1;      // dv in -1..2
        const bool v0ok = dv <= 1, v1ok = dv >= 0;
        const char* ap0 = ws + (size_t)(ku * 3 + dv + 1) * 5120 + (size_t)lane * 16;
        const char* ap1 = ws + (size_t)(ku * 3 + dv) * 5120 + (size_t)lane * 16;
        bf16x8 afr0[5], afr1[5];
        #pragma unroll
        for (int s = 0; s < 5; ++s) {
            afr0[s] = v0ok ? *(const bf16x8*)(ap0 + s * 1024) : zfr;
            afr1[s] = v1ok ? *(const bf16x8*)(ap1 + s * 1024) : zfr;
        }

        const char* bp = lds + bufsel * SLAB_B + wv_off;
        #define TIMM(ti_) (((ti_) / 3) * 3328 + ((ti_) % 3) * 128)

        // software-pipelined B-fragment reads: tile ti+1 loads issue before tile ti MFMAs
        bf16x8 b0[5], b1[5];
        #pragma unroll
        for (int s = 0; s < 5; ++s) b0[s] = *(const bf16x8*)(bp + TIMM(0) + laneoff[s]);
        #pragma unroll
        for (int ti = 0; ti < 9; ++ti) {
            const bf16x8* curb = (ti & 1) ? b1 : b0;
            bf16x8* nxtb = (ti & 1) ? b0 : b1;
            if (ti < 8) {
                #pragma unroll
                for (int s = 0; s < 5; ++s)
                    nxtb[s] = *(const bf16x8*)(bp + TIMM(ti + 1) + laneoff[s]);
            }
            __builtin_amdgcn_s_setprio(1);
            #pragma unroll
            for (int s = 0; s < 5; ++s) {
                acc0[ti] = __builtin_amdgcn_mfma_f32_16x16x32_bf16(afr0[s], curb[s], acc0[ti], 0, 0, 0);
                acc1[ti] = __builtin_amdgcn_mfma_f32_16x16x32_bf16(afr1[s], curb[s], acc1[ti], 0, 0, 0);
            }
            __builtin_amdgcn_s_setprio(0);
        }
        __syncthreads();   // drains prefetch + read/write fence
        if (nxt < 0) break;
        cur = nxt; bufsel ^= 1;
    }

    // epilogue: C col = lane&15 -> (dh,dw); row = g*4+r -> c_out ; two v-slabs
    float bv[4];
    #pragma unroll
    for (int r = 0; r < 4; ++r) bv[r] = bias[g * 4 + r];
    float* outp0 = out + (size_t)nb * 16 * CISTRIDE + (size_t)(u * S + v0) * PLANE;
    float* outp1 = outp0 + PLANE;
    #pragma unroll
    for (int ti = 0; ti < 9; ++ti) {
        int h0 = ((ti / 3) + (wvid >> 1) * 3) * 4;
        int w0 = ((ti % 3) + (wvid & 1) * 3) * 4;
        int pos = (h0 + dh) * S + (w0 + dw);
        #pragma unroll
        for (int r = 0; r < 4; ++r) {
            outp0[(size_t)(g * 4 + r) * CISTRIDE + pos] = acc0[ti][r] + bv[r];
            outp1[(size_t)(g * 4 + r) * CISTRIDE + pos] = acc1[ti][r] + bv[r];
        }
    }
}

extern "C" void kernel_launch(void* const* d_in, const int* in_sizes, int n_in,
                              void* d_out, int out_size, void* d_ws, size_t ws_size,
                              hipStream_t stream) {
    const float* in   = (const float*)d_in[0];
    const float* wgt  = (const float*)d_in[1];
    const float* bias = (const float*)d_in[2];
    float* out        = (float*)d_out;
    char* ws          = (char*)d_ws;

    pack_in<<<dim3(2 * PLANE), dim3(256), 0, stream>>>(in, wgt, ws);
    conv4d_main<<<dim3(576), dim3(256), 0, stream>>>(ws, bias, out);
}

// Round 8
// 77.426 us; speedup vs baseline: 1.1664x; 1.1664x over previous
//
#include <hip/hip_runtime.h>

#define S 24
#define PLANE 576
#define CISTRIDE 331776          // floats per (n,ci)
#define SLAB_B 21632             // full padded slab: 676 positions * 32 B
#define HSLAB_B 11648            // half-slab buffer: 14 rows * 26 * 32 B
#define HOFF 9984                // 12 rows * 832 B
#define A_BYTES 46080            // 9 taps * 5 steps * 64 lanes * 16 B
#define WS_SLABS A_BYTES

typedef __attribute__((ext_vector_type(8))) short bf16x8;
typedef __attribute__((ext_vector_type(4))) float f32x4;

__device__ __forceinline__ ushort f2bf(float f) {   // round-to-nearest-even
    unsigned int u = __builtin_bit_cast(unsigned int, f);
    unsigned int r = u + 0x7fffu + ((u >> 16) & 1u);
    return (ushort)(r >> 16);
}

// slot swizzle: byte offset for (row,col,half) = ((row*26+col)*32 + half*16) ^ ((row&3)<<4)
__device__ __forceinline__ int swz(int row, int col, int half) {
    return (((row * 26 + col) * 32) + half * 16) ^ ((row & 3) << 4);
}

// ---------------- prepass: pack input slabs via LDS transpose (+ weights from block 0) ----
__global__ void __launch_bounds__(256)
pack_in(const float* __restrict__ in, const float* __restrict__ wgt, char* __restrict__ ws) {
    __shared__ unsigned lds_t[16][288];   // [ci][pos-pair] packed bf16x2

    const int b = blockIdx.x;             // 1152 slabs
    const int nb = b / PLANE, uv = b % PLANE;
    const float* src = in + (size_t)nb * 16 * CISTRIDE + (size_t)uv * PLANE;
    char* dst = ws + WS_SLABS + (size_t)b * SLAB_B;
    const int t = threadIdx.x;

    #pragma unroll
    for (int i = 0; i < 9; ++i) {
        int flat = i * 256 + t;           // 0..2303 float4 chunks
        int ci = flat / 144, q4 = flat % 144;
        float4 f = *(const float4*)(src + (size_t)ci * CISTRIDE + 4 * q4);
        uint2 pk;
        pk.x = (unsigned)f2bf(f.x) | ((unsigned)f2bf(f.y) << 16);
        pk.y = (unsigned)f2bf(f.z) | ((unsigned)f2bf(f.w) << 16);
        *(uint2*)&lds_t[ci][2 * q4] = pk;
    }
    __syncthreads();

    #pragma unroll
    for (int i = 0; i < 6; ++i) {
        int c = i * 256 + t;              // chunk index 0..1351
        if (c < 1352) {
            int k = c >> 2;
            int row = k / 13;             // pairs never cross a row (26 even)
            int pos2 = c ^ (row & 3);
            int pos = pos2 >> 1, h = pos2 & 1;
            int col = pos - row * 26;
            uint4 o = make_uint4(0, 0, 0, 0);
            if (row >= 1 && row <= 24 && col >= 1 && col <= 24) {
                int q = (row - 1) * 24 + (col - 1);
                int q2 = q >> 1, odd = q & 1;
                #pragma unroll
                for (int kk = 0; kk < 4; ++kk) {
                    unsigned a = lds_t[8 * h + 2 * kk][q2];
                    unsigned bb = lds_t[8 * h + 2 * kk + 1][q2];
                    unsigned val = odd ? ((a >> 16) | (bb & 0xffff0000u))
                                       : ((a & 0xffffu) | (bb << 16));
                    ((unsigned*)&o)[kk] = val;
                }
            }
            *(uint4*)(dst + (size_t)c * 16) = o;
        }
    }

    if (b == 0) {                        // weight A-fragments -> ws[0..A_BYTES)
        for (int i = t; i < 2880; i += 256) {
            int step = i >> 6;           // 0..44
            int tap = step / 5, s = step % 5;
            int lane = i & 63;
            int co = lane & 15, gA = lane >> 4;
            int o = 2 * s + (gA >> 1);
            int cib = (gA & 1) * 8;
            ushort vals[8];
            #pragma unroll
            for (int j = 0; j < 8; ++j)
                vals[j] = (o <= 8) ? f2bf(wgt[co * 1296 + (cib + j) * 81 + tap * 9 + o]) : (ushort)0;
            uint4 pk;
            pk.x = vals[0] | ((unsigned)vals[1] << 16);
            pk.y = vals[2] | ((unsigned)vals[3] << 16);
            pk.z = vals[4] | ((unsigned)vals[5] << 16);
            pk.w = vals[6] | ((unsigned)vals[7] << 16);
            *(uint4*)(ws + (size_t)i * 16) = pk;
        }
    }
}

// ------------- main: G=2 v-adjacent outputs, h-split halves, 192 thr, 6 blocks/CU -------------
__global__ void __launch_bounds__(192, 4)
conv4d_main(const char* __restrict__ ws, const float* __restrict__ bias,
            float* __restrict__ out) {
    __shared__ __align__(16) char lds[2 * HSLAB_B];   // 23296 B double buffer

    const int t = threadIdx.x, lane = t & 63, wvid = t >> 6;   // 3 waves
    // XCD-chunked bijective swizzle: 1152 ids, 8 XCDs x 144 contiguous
    const int braw = blockIdx.x;
    const int b = (braw & 7) * 144 + (braw >> 3);
    const int nb = b / 576, rem = b % 576;
    const int u = rem / 24, rem2 = rem % 24;
    const int v0 = (rem2 >> 1) * 2, hh = rem2 & 1;    // hh innermost: halves share slab window

    const int n16 = lane & 15, g = lane >> 4;
    const int dh = n16 >> 3, dw = n16 & 7;            // 2x8 position tile
    const int half = g & 1, osel = g >> 1;

    // lanepart tables per tile-row parity (rowbase&3 = 2*trp)
    int laneoff[2][5];
    #pragma unroll
    for (int trp = 0; trp < 2; ++trp)
        #pragma unroll
        for (int s = 0; s < 5; ++s) {
            int o = 2 * s + osel; if (o > 8) o = 8;   // K-tail clamp (A is zero there)
            int kh = o / 3, kw = o % 3;
            int r_off = dh + kh, c_off = dw + kw;
            int lin = (r_off * 26 + c_off) * 32 + half * 16;
            laneoff[trp][s] = lin ^ ((((trp << 1) + r_off) & 3) << 4);
        }

    f32x4 acc0[6], acc1[6];
    #pragma unroll
    for (int i = 0; i < 6; ++i) { acc0[i] = (f32x4){0,0,0,0}; acc1[i] = (f32x4){0,0,0,0}; }

    // valid-slab mask: i = 4*(uu-u+1) + (vv-v0+1)   (independent of hh)
    unsigned mask = 0;
    #pragma unroll
    for (int i = 0; i < 12; ++i) {
        int uu = u + (i >> 2) - 1, vv = v0 + (i & 3) - 1;
        if (uu >= 0 && uu < S && vv >= 0 && vv < S) mask |= 1u << i;
    }

    const char* slabs = ws + WS_SLABS;
    const int srcoff = hh * HOFF;
    #define SLAB_PTR(i_) (slabs + ((size_t)nb * PLANE + (u + ((i_) >> 2) - 1) * S + (v0 + ((i_) & 3) - 1)) * SLAB_B + srcoff)

    #define STAGE(bufsel_, src_) do {                                              \
        const char* _s = (src_);                                                   \
        _Pragma("unroll")                                                          \
        for (int r2 = 0; r2 < 4; ++r2) {                                           \
            int chunk = r2 * 192 + t;                                              \
            if (r2 < 3 || t < 152)                                                 \
                __builtin_amdgcn_global_load_lds(                                  \
                    (const __attribute__((address_space(1))) unsigned int*)(_s + (size_t)chunk * 16), \
                    (__attribute__((address_space(3))) unsigned int*)(lds + (bufsel_) * HSLAB_B + chunk * 16), \
                    16, 0, 0);                                                     \
        }                                                                          \
    } while (0)

    const bf16x8 zfr = {0,0,0,0,0,0,0,0};

    int cur = __ffs(mask) - 1;
    int bufsel = 0;
    STAGE(0, SLAB_PTR(cur));
    __syncthreads();

    while (1) {
        unsigned remm = mask >> (cur + 1);
        int nxt = remm ? (cur + 1 + __ffs(remm) - 1) : -1;
        if (nxt >= 0) STAGE(bufsel ^ 1, SLAB_PTR(nxt));   // overlaps compute below

        const int ku = cur >> 2, dv = (cur & 3) - 1;      // dv in -1..2
        const bool v0ok = dv <= 1, v1ok = dv >= 0;
        const char* ap0 = ws + (size_t)(ku * 3 + dv + 1) * 5120 + (size_t)lane * 16;
        const char* ap1 = ws + (size_t)(ku * 3 + dv) * 5120 + (size_t)lane * 16;
        bf16x8 afr0[5], afr1[5];
        #pragma unroll
        for (int s = 0; s < 5; ++s) {
            afr0[s] = v0ok ? *(const bf16x8*)(ap0 + s * 1024) : zfr;
            afr1[s] = v1ok ? *(const bf16x8*)(ap1 + s * 1024) : zfr;
        }

        const char* bp = lds + bufsel * HSLAB_B + wvid * 3328;   // wave rows 4*wvid..
        #pragma unroll
        for (int tr = 0; tr < 2; ++tr) {
            #pragma unroll
            for (int tc = 0; tc < 3; ++tc) {
                const int ti = tr * 3 + tc;
                const char* bpt = bp + tr * 1664 + tc * 256;
                #pragma unroll
                for (int s = 0; s < 5; ++s) {
                    bf16x8 bfr = *(const bf16x8*)(bpt + laneoff[tr][s]);
                    acc0[ti] = __builtin_amdgcn_mfma_f32_16x16x32_bf16(afr0[s], bfr, acc0[ti], 0, 0, 0);
                    acc1[ti] = __builtin_amdgcn_mfma_f32_16x16x32_bf16(afr1[s], bfr, acc1[ti], 0, 0, 0);
                }
            }
        }
        __syncthreads();   // drains prefetch + read/write fence
        if (nxt < 0) break;
        cur = nxt; bufsel ^= 1;
    }

    // epilogue: C col = lane&15 -> (dh,dw); row = g*4+r -> c_out ; two v-slabs
    float bv[4];
    #pragma unroll
    for (int r = 0; r < 4; ++r) bv[r] = bias[g * 4 + r];
    float* outp0 = out + (size_t)nb * 16 * CISTRIDE + (size_t)(u * S + v0) * PLANE;
    float* outp1 = outp0 + PLANE;
    #pragma unroll
    for (int tr = 0; tr < 2; ++tr) {
        #pragma unroll
        for (int tc = 0; tc < 3; ++tc) {
            const int ti = tr * 3 + tc;
            int row = hh * 12 + wvid * 4 + tr * 2 + dh;
            int col = tc * 8 + dw;
            int pos = row * S + col;
            #pragma unroll
            for (int r = 0; r < 4; ++r) {
                outp0[(size_t)(g * 4 + r) * CISTRIDE + pos] = acc0[ti][r] + bv[r];
                outp1[(size_t)(g * 4 + r) * CISTRIDE + pos] = acc1[ti][r] + bv[r];
            }
        }
    }
}

extern "C" void kernel_launch(void* const* d_in, const int* in_sizes, int n_in,
                              void* d_out, int out_size, void* d_ws, size_t ws_size,
                              hipStream_t stream) {
    const float* in   = (const float*)d_in[0];
    const float* wgt  = (const float*)d_in[1];
    const float* bias = (const float*)d_in[2];
    float* out        = (float*)d_out;
    char* ws          = (char*)d_ws;

    pack_in<<<dim3(2 * PLANE), dim3(256), 0, stream>>>(in, wgt, ws);
    conv4d_main<<<dim3(1152), dim3(192), 0, stream>>>(ws, bias, out);
}